// Round 1
// baseline (50.689 us; speedup 1.0000x reference)
//
#include <hip/hip_runtime.h>
#include <hip/hip_bf16.h>

#define TT 1024
#define AA 16
#define DTS 0.4f
#define EPSV 1e-6f

// diff = (ado - ado_wo); second derivative along t, zero at ends
__device__ __forceinline__ float dd_comp(const float* __restrict__ a,
                                         const float* __restrict__ b,
                                         int base, int t, int c) {
    if (t == 0 || t == TT - 1) return 0.0f;
    int i = base + t * 2 + c;
    float dm = a[i - 2] - b[i - 2];
    float d0 = a[i]     - b[i];
    float dp = a[i + 2] - b[i + 2];
    return (dm - 2.0f * d0 + dp) * (1.0f / (DTS * DTS));
}

// ws[t*32 + j*2 + c] = w[j,t] * s[j,t,c]
//   w[j,t]   = sum_a 1/norm(diff''[a,j,t,:])   (0 where norm < eps)
//   s[j,t,c] = sum_m diff''[j,m,t,c]
__global__ __launch_bounds__(256) void ws_kernel(const float* __restrict__ ado,
                                                 const float* __restrict__ ado_wo,
                                                 float* __restrict__ ws) {
    int idx = blockIdx.x * blockDim.x + threadIdx.x;  // [0, 16*1024)
    if (idx >= AA * TT) return;
    int j = idx / TT;
    int t = idx % TT;

    float w = 0.0f;
    #pragma unroll
    for (int a = 0; a < AA; ++a) {
        int base = (a * AA + j) * TT * 2;
        float dx = dd_comp(ado, ado_wo, base, t, 0);
        float dy = dd_comp(ado, ado_wo, base, t, 1);
        float n = sqrtf(dx * dx + dy * dy);
        w += (n < EPSV) ? 0.0f : (1.0f / n);
    }

    float sx = 0.0f, sy = 0.0f;
    #pragma unroll
    for (int m = 0; m < AA; ++m) {
        int base = (j * AA + m) * TT * 2;
        sx += dd_comp(ado, ado_wo, base, t, 0);
        sy += dd_comp(ado, ado_wo, base, t, 1);
    }

    ws[t * 32 + j * 2 + 0] = w * sx;
    ws[t * 32 + j * 2 + 1] = w * sy;
}

// One block per k. out[2k+c] = sum_{u,j} pg[k,u,j,c] * coef(u,j,c,k)
// coef = ws[j,u+1,c]*[k-2<=u<=T-3] - 2*ws[j,u,c]*[k-1<=u<=T-2]
//        + ws[j,0,c]*[k==1 && u==T-1]
__global__ __launch_bounds__(256) void grad_kernel(const float* __restrict__ pg,
                                                   const float* __restrict__ ws,
                                                   float* __restrict__ out) {
    const int k = blockIdx.x;
    const int tid = threadIdx.x;

    if (k == 0) {  // mask requires k >= 1
        if (tid < 2) out[tid] = 0.0f;
        return;
    }

    const float* __restrict__ row = pg + (size_t)k * (TT * AA * 2);

    float accx = 0.0f, accy = 0.0f;

    // 1024*16*2 = 32768 floats = 8192 float4 per row; 32 iters per thread
    for (int i = tid; i < (TT * AA * 2) / 4; i += 256) {
        int f = i * 4;
        int u = f >> 5;        // t index (32 floats per t)
        int rem = f & 31;      // position within the 32-float (j,c) vector

        float4 p = *reinterpret_cast<const float4*>(row + f);
        float cx0 = 0.0f, cy0 = 0.0f, cx1 = 0.0f, cy1 = 0.0f;

        if (u >= k - 1 && u <= TT - 2) {
            float4 wc = *reinterpret_cast<const float4*>(ws + u * 32 + rem);
            cx0 -= 2.0f * wc.x; cy0 -= 2.0f * wc.y;
            cx1 -= 2.0f * wc.z; cy1 -= 2.0f * wc.w;
        }
        if (u >= k - 2 && u <= TT - 3) {
            float4 wn = *reinterpret_cast<const float4*>(ws + (u + 1) * 32 + rem);
            cx0 += wn.x; cy0 += wn.y;
            cx1 += wn.z; cy1 += wn.w;
        }
        if (k == 1 && u == TT - 1) {
            float4 w0 = *reinterpret_cast<const float4*>(ws + rem);
            cx0 += w0.x; cy0 += w0.y;
            cx1 += w0.z; cy1 += w0.w;
        }

        accx += p.x * cx0 + p.z * cx1;
        accy += p.y * cy0 + p.w * cy1;
    }

    // wave64 shuffle reduce
    for (int off = 32; off > 0; off >>= 1) {
        accx += __shfl_down(accx, off, 64);
        accy += __shfl_down(accy, off, 64);
    }
    __shared__ float sx[4], sy[4];
    int wave = tid >> 6;
    int lane = tid & 63;
    if (lane == 0) { sx[wave] = accx; sy[wave] = accy; }
    __syncthreads();
    if (tid == 0) {
        float rx = sx[0] + sx[1] + sx[2] + sx[3];
        float ry = sy[0] + sy[1] + sy[2] + sy[3];
        out[2 * k + 0] = rx;
        out[2 * k + 1] = ry;
    }
}

extern "C" void kernel_launch(void* const* d_in, const int* in_sizes, int n_in,
                              void* d_out, int out_size, void* d_ws, size_t ws_size,
                              hipStream_t stream) {
    const float* ado    = (const float*)d_in[0];
    const float* ado_wo = (const float*)d_in[1];
    const float* pg     = (const float*)d_in[2];
    float* out = (float*)d_out;
    float* ws  = (float*)d_ws;  // 1024*16*2 floats = 128 KB

    ws_kernel<<<(AA * TT + 255) / 256, 256, 0, stream>>>(ado, ado_wo, ws);
    grad_kernel<<<TT, 256, 0, stream>>>(pg, ws, out);
}

// Round 2
// 40.142 us; speedup vs baseline: 1.2627x; 1.2627x over previous
//
#include <hip/hip_runtime.h>
#include <hip/hip_bf16.h>

#define TT 1024
#define AA 16
#define DTS 0.4f
#define EPSV 1e-6f

// diff = (ado - ado_wo); second derivative along t, zero at ends
__device__ __forceinline__ float dd_comp(const float* __restrict__ a,
                                         const float* __restrict__ b,
                                         int base, int t, int c) {
    if (t == 0 || t == TT - 1) return 0.0f;
    int i = base + t * 2 + c;
    float dm = a[i - 2] - b[i - 2];
    float d0 = a[i]     - b[i];
    float dp = a[i + 2] - b[i + 2];
    return (dm - 2.0f * d0 + dp) * (1.0f / (DTS * DTS));
}

// ws[t*32 + j*2 + c] = w[j,t] * s[j,t,c]
//   w[j,t]   = sum_a 1/norm(diff''[a,j,t,:])   (0 where norm < eps)
//   s[j,t,c] = sum_m diff''[j,m,t,c]
// Note ws[·, t=0] = ws[·, t=T-1] = 0 exactly (dd is zero-padded at ends).
__global__ __launch_bounds__(256) void ws_kernel(const float* __restrict__ ado,
                                                 const float* __restrict__ ado_wo,
                                                 float* __restrict__ ws) {
    int idx = blockIdx.x * blockDim.x + threadIdx.x;  // [0, 16*1024)
    if (idx >= AA * TT) return;
    int j = idx / TT;
    int t = idx % TT;

    float w = 0.0f;
    #pragma unroll
    for (int a = 0; a < AA; ++a) {
        int base = (a * AA + j) * TT * 2;
        float dx = dd_comp(ado, ado_wo, base, t, 0);
        float dy = dd_comp(ado, ado_wo, base, t, 1);
        float n = sqrtf(dx * dx + dy * dy);
        w += (n < EPSV) ? 0.0f : (1.0f / n);
    }

    float sx = 0.0f, sy = 0.0f;
    #pragma unroll
    for (int m = 0; m < AA; ++m) {
        int base = (j * AA + m) * TT * 2;
        sx += dd_comp(ado, ado_wo, base, t, 0);
        sy += dd_comp(ado, ado_wo, base, t, 1);
    }

    ws[t * 32 + j * 2 + 0] = w * sx;
    ws[t * 32 + j * 2 + 1] = w * sy;
}

// coef[u,j,c] = ws[u+1,j,c] - 2*ws[u,j,c]   (u < T-1); coef[T-1] = 0 (unused)
__global__ __launch_bounds__(256) void coef_kernel(const float* __restrict__ ws,
                                                   float* __restrict__ coef) {
    int i = blockIdx.x * 256 + threadIdx.x;  // float4 index, 8192 total
    const float4* w4 = reinterpret_cast<const float4*>(ws);
    float4 w = w4[i];
    float4 r;
    if (i < (TT - 1) * 8) {
        float4 wn = w4[i + 8];
        r.x = wn.x - 2.0f * w.x;
        r.y = wn.y - 2.0f * w.y;
        r.z = wn.z - 2.0f * w.z;
        r.w = wn.w - 2.0f * w.w;
    } else {
        r.x = r.y = r.z = r.w = 0.0f;
    }
    reinterpret_cast<float4*>(coef)[i] = r;
}

// out[2k+c] = sum_{u=k-1}^{T-2} sum_j pg[k,u,j,c]*coef[u,j,c]
//           + sum_j pg[k,k-2,j,c]*ws[k-1,j,c]   (k>=2, boundary slice)
// Block b handles k1=b+1 and k2=1023-b (equal total work ~= T slices).
__global__ __launch_bounds__(512) void grad_kernel(const float* __restrict__ pg,
                                                   const float* __restrict__ ws,
                                                   const float* __restrict__ coef,
                                                   float* __restrict__ out) {
    const int b = blockIdx.x;
    const int tid = threadIdx.x;
    __shared__ float sx[8], sy[8];

    if (b == 0 && tid < 2) out[tid] = 0.0f;  // k = 0 masked out

    const int k1 = b + 1;          // 1..512
    const int k2 = TT - 1 - b;     // 1023..512

    for (int pass = 0; pass < 2; ++pass) {
        if (pass && k2 == k1) break;   // b==511 duplicate
        const int k = pass ? k2 : k1;
        const float* __restrict__ row = pg + (size_t)k * (TT * AA * 2);

        float accx = 0.0f, accy = 0.0f;

        // boundary slice u = k-2: coefficient is ws[k-1] only
        if (k >= 2 && tid < 8) {
            int f = (k - 2) * 32 + tid * 4;
            float4 p  = *reinterpret_cast<const float4*>(row + f);
            float4 wv = *reinterpret_cast<const float4*>(ws + (k - 1) * 32 + tid * 4);
            accx += p.x * wv.x + p.z * wv.z;
            accy += p.y * wv.y + p.w * wv.w;
        }

        // main suffix u in [k-1, T-2]
        for (int i = (k - 1) * 8 + tid; i < (TT - 1) * 8; i += 512) {
            int f = i * 4;
            float4 p = *reinterpret_cast<const float4*>(row + f);
            float4 c = *reinterpret_cast<const float4*>(coef + f);
            accx += p.x * c.x + p.z * c.z;
            accy += p.y * c.y + p.w * c.w;
        }

        // wave64 shuffle reduce
        for (int off = 32; off > 0; off >>= 1) {
            accx += __shfl_down(accx, off, 64);
            accy += __shfl_down(accy, off, 64);
        }
        if (pass) __syncthreads();  // LDS reuse barrier (uniform: break above is uniform)
        int wave = tid >> 6, lane = tid & 63;
        if (lane == 0) { sx[wave] = accx; sy[wave] = accy; }
        __syncthreads();
        if (tid == 0) {
            float rx = 0.0f, ry = 0.0f;
            #pragma unroll
            for (int w2 = 0; w2 < 8; ++w2) { rx += sx[w2]; ry += sy[w2]; }
            out[2 * k + 0] = rx;
            out[2 * k + 1] = ry;
        }
    }
}

extern "C" void kernel_launch(void* const* d_in, const int* in_sizes, int n_in,
                              void* d_out, int out_size, void* d_ws, size_t ws_size,
                              hipStream_t stream) {
    const float* ado    = (const float*)d_in[0];
    const float* ado_wo = (const float*)d_in[1];
    const float* pg     = (const float*)d_in[2];
    float* out  = (float*)d_out;
    float* ws   = (float*)d_ws;                    // 32768 floats = 128 KB
    float* coef = (float*)d_ws + TT * AA * 2;      // 32768 floats = 128 KB

    ws_kernel<<<(AA * TT + 255) / 256, 256, 0, stream>>>(ado, ado_wo, ws);
    coef_kernel<<<(TT * AA * 2 / 4) / 256, 256, 0, stream>>>(ws, coef);
    grad_kernel<<<512, 512, 0, stream>>>(pg, ws, coef, out);
}

// Round 3
// 37.036 us; speedup vs baseline: 1.3686x; 1.0839x over previous
//
#include <hip/hip_runtime.h>
#include <hip/hip_bf16.h>

#define TT 1024
#define AA 16
#define DTS 0.4f
#define EPSV 1e-6f

// diff = (ado - ado_wo); second derivative along t, zero at ends
__device__ __forceinline__ float dd_comp(const float* __restrict__ a,
                                         const float* __restrict__ b,
                                         int base, int t, int c) {
    if (t == 0 || t == TT - 1) return 0.0f;
    int i = base + t * 2 + c;
    float dm = a[i - 2] - b[i - 2];
    float d0 = a[i]     - b[i];
    float dp = a[i + 2] - b[i + 2];
    return (dm - 2.0f * d0 + dp) * (1.0f / (DTS * DTS));
}

// Fused: ws[t*32+j*2+c] = w[j,t]*s[j,t,c];  coef[u*32+j*2+c] = ws[u+1]-2*ws[u]
// Block owns 4 t-slices (plus 1 redundant boundary slice). 256 threads =
// 64 (j,dt) items x 4 partials over the a/m loops; 4-lane shuffle reduce.
__global__ __launch_bounds__(256) void wscoef_kernel(const float* __restrict__ ado,
                                                     const float* __restrict__ ado_wo,
                                                     float* __restrict__ ws,
                                                     float* __restrict__ coef) {
    const int t0 = blockIdx.x * 4;
    const int tid = threadIdx.x;
    const int item = tid >> 2;   // 0..63
    const int part = tid & 3;    // 0..3
    const int j = item & 15;
    const int dt = item >> 4;    // 0..3

    __shared__ float lws[5][16][2];

    // compute partial (over 4 a's / 4 m's) for (j, t), reduce, leader -> LDS slot
    auto compute = [&](int t, int slot) {
        float w = 0.0f, sx = 0.0f, sy = 0.0f;
        if (t < TT) {
            #pragma unroll
            for (int aa = 0; aa < 4; ++aa) {
                int a = part * 4 + aa;
                int base = (a * AA + j) * TT * 2;
                float dx = dd_comp(ado, ado_wo, base, t, 0);
                float dy = dd_comp(ado, ado_wo, base, t, 1);
                float n = sqrtf(dx * dx + dy * dy);
                w += (n < EPSV) ? 0.0f : (1.0f / n);
            }
            #pragma unroll
            for (int mm = 0; mm < 4; ++mm) {
                int m = part * 4 + mm;
                int base = (j * AA + m) * TT * 2;
                sx += dd_comp(ado, ado_wo, base, t, 0);
                sy += dd_comp(ado, ado_wo, base, t, 1);
            }
        }
        // reduce across the 4 consecutive lanes of this item
        w  += __shfl_down(w, 1, 64);  w  += __shfl_down(w, 2, 64);
        sx += __shfl_down(sx, 1, 64); sx += __shfl_down(sx, 2, 64);
        sy += __shfl_down(sy, 1, 64); sy += __shfl_down(sy, 2, 64);
        if (part == 0) {
            lws[slot][j][0] = w * sx;
            lws[slot][j][1] = w * sy;
        }
    };

    compute(t0 + dt, dt);
    if (item < 16) compute(t0 + 4, 4);   // wave 0 (dt==0, j==item) does the boundary slice
    __syncthreads();

    // threads 0..127 write coef chunk; threads 128..255 write ws chunk (coalesced)
    if (tid < 128) {
        int du = tid >> 5, rem = tid & 31;
        int j2 = rem >> 1, c = rem & 1;
        int u = t0 + du;
        float v = (u < TT - 1) ? (lws[du + 1][j2][c] - 2.0f * lws[du][j2][c]) : 0.0f;
        coef[u * 32 + rem] = v;
    } else {
        int tt = tid - 128;
        int du = tt >> 5, rem = tt & 31;
        int j2 = rem >> 1, c = rem & 1;
        ws[(t0 + du) * 32 + rem] = lws[du][j2][c];
    }
}

// out[2k+c] = sum_{u=k-1}^{T-2} sum_j pg[k,u,j,c]*coef[u,j,c]
//           + sum_j pg[k,k-2,j,c]*ws[k-1,j,c]   (k>=2 boundary slice)
// Block b handles k1=b+1 and k2=1023-b (equal total work).
__global__ __launch_bounds__(512) void grad_kernel(const float* __restrict__ pg,
                                                   const float* __restrict__ ws,
                                                   const float* __restrict__ coef,
                                                   float* __restrict__ out) {
    const int b = blockIdx.x;
    const int tid = threadIdx.x;
    __shared__ float sx[8], sy[8];

    if (b == 0 && tid < 2) out[tid] = 0.0f;  // k = 0 masked out

    const int k1 = b + 1;          // 1..512
    const int k2 = TT - 1 - b;     // 1023..512
    const float4* __restrict__ coef4 = reinterpret_cast<const float4*>(coef);

    for (int pass = 0; pass < 2; ++pass) {
        if (pass && k2 == k1) break;   // b==511 duplicate (uniform branch)
        const int k = pass ? k2 : k1;
        const float4* __restrict__ row4 =
            reinterpret_cast<const float4*>(pg + (size_t)k * (TT * AA * 2));

        float accx = 0.0f, accy = 0.0f;

        // boundary slice u = k-2: coefficient is ws[k-1] only
        if (k >= 2 && tid < 8) {
            int q = (k - 2) * 8 + tid;
            float4 p  = row4[q];
            float4 wv = *reinterpret_cast<const float4*>(ws + (k - 1) * 32 + tid * 4);
            accx += p.x * wv.x + p.z * wv.z;
            accy += p.y * wv.y + p.w * wv.w;
        }

        // main suffix u in [k-1, T-2]; 2-way unrolled for ILP
        const int end = (TT - 1) * 8;
        int i = (k - 1) * 8 + tid;
        for (; i + 512 < end; i += 1024) {
            float4 p0 = row4[i];        float4 c0 = coef4[i];
            float4 p1 = row4[i + 512];  float4 c1 = coef4[i + 512];
            accx += p0.x * c0.x + p0.z * c0.z;
            accy += p0.y * c0.y + p0.w * c0.w;
            accx += p1.x * c1.x + p1.z * c1.z;
            accy += p1.y * c1.y + p1.w * c1.w;
        }
        if (i < end) {
            float4 p0 = row4[i];  float4 c0 = coef4[i];
            accx += p0.x * c0.x + p0.z * c0.z;
            accy += p0.y * c0.y + p0.w * c0.w;
        }

        // wave64 shuffle reduce
        for (int off = 32; off > 0; off >>= 1) {
            accx += __shfl_down(accx, off, 64);
            accy += __shfl_down(accy, off, 64);
        }
        if (pass) __syncthreads();  // LDS reuse barrier (uniform)
        int wave = tid >> 6, lane = tid & 63;
        if (lane == 0) { sx[wave] = accx; sy[wave] = accy; }
        __syncthreads();
        if (tid == 0) {
            float rx = 0.0f, ry = 0.0f;
            #pragma unroll
            for (int w2 = 0; w2 < 8; ++w2) { rx += sx[w2]; ry += sy[w2]; }
            out[2 * k + 0] = rx;
            out[2 * k + 1] = ry;
        }
    }
}

extern "C" void kernel_launch(void* const* d_in, const int* in_sizes, int n_in,
                              void* d_out, int out_size, void* d_ws, size_t ws_size,
                              hipStream_t stream) {
    const float* ado    = (const float*)d_in[0];
    const float* ado_wo = (const float*)d_in[1];
    const float* pg     = (const float*)d_in[2];
    float* out  = (float*)d_out;
    float* ws   = (float*)d_ws;                    // 32768 floats = 128 KB
    float* coef = (float*)d_ws + TT * AA * 2;      // 32768 floats = 128 KB

    wscoef_kernel<<<TT / 4, 256, 0, stream>>>(ado, ado_wo, ws, coef);
    grad_kernel<<<512, 512, 0, stream>>>(pg, ws, coef, out);
}

// Round 4
// 22.999 us; speedup vs baseline: 2.2040x; 1.6104x over previous
//
#include <hip/hip_runtime.h>
#include <hip/hip_bf16.h>

#define TT 1024
#define AA 16
#define DTS 0.4f
#define EPSV 1e-6f

// dd components (x,y) of (ado-ado_wo)'' for flat row `row` at time t; 0 at ends
__device__ __forceinline__ float2 dd2(const float2* __restrict__ A,
                                      const float2* __restrict__ B,
                                      int row, int t) {
    if (t <= 0 || t >= TT - 1) return make_float2(0.f, 0.f);
    const float2* a = A + row * TT + t;
    const float2* b = B + row * TT + t;
    float2 am = a[-1], a0 = a[0], ap = a[1];
    float2 bm = b[-1], b0 = b[0], bp = b[1];
    const float s = 1.0f / (DTS * DTS);
    float2 r;
    r.x = ((am.x - bm.x) - 2.f * (a0.x - b0.x) + (ap.x - bp.x)) * s;
    r.y = ((am.y - bm.y) - 2.f * (a0.y - b0.y) + (ap.y - bp.y)) * s;
    return r;
}

// Block = (j, 64-wide t-chunk): 16*16 = 256 blocks, 4 waves = 4 a/m-quarters.
// Lane = t offset -> all global loads coalesced float2 along t.
// ws[t*32+j*2+c] = w[j,t]*s[j,t,c];  coef[u] = ws[u+1] - 2*ws[u]
__global__ __launch_bounds__(256) void wscoef_kernel(const float* __restrict__ ado,
                                                     const float* __restrict__ ado_wo,
                                                     float* __restrict__ ws,
                                                     float* __restrict__ coef) {
    const int bid = blockIdx.x;
    const int j = bid >> 4;
    const int chunk = bid & 15;
    const int tid = threadIdx.x;
    const int sub = tid >> 6;      // wave = a/m quarter
    const int lane = tid & 63;
    const int t = chunk * 64 + lane;
    const int tb = chunk * 64 + 64;     // boundary t for coef of last lane
    const float2* A = (const float2*)ado;
    const float2* B = (const float2*)ado_wo;

    float w = 0.f, sx = 0.f, sy = 0.f;
    float wb = 0.f, sbx = 0.f, sby = 0.f;

    #pragma unroll
    for (int q = 0; q < 4; ++q) {
        int a = sub * 4 + q;
        int rowW = a * AA + j;   // w: reduce over first index
        float2 d = dd2(A, B, rowW, t);
        float n = sqrtf(d.x * d.x + d.y * d.y);
        w += (n < EPSV) ? 0.f : 1.f / n;
        int rowS = j * AA + a;   // s: reduce over second index
        float2 e = dd2(A, B, rowS, t);
        sx += e.x; sy += e.y;
        if (tb < TT) {           // broadcast loads (uniform addr across lanes)
            float2 db = dd2(A, B, rowW, tb);
            float nb = sqrtf(db.x * db.x + db.y * db.y);
            wb += (nb < EPSV) ? 0.f : 1.f / nb;
            float2 eb = dd2(A, B, rowS, tb);
            sbx += eb.x; sby += eb.y;
        }
    }

    __shared__ float lw[4][64], lsx[4][64], lsy[4][64];
    __shared__ float lwb[4], lsbx[4], lsby[4];
    lw[sub][lane] = w; lsx[sub][lane] = sx; lsy[sub][lane] = sy;
    if (lane == 0) { lwb[sub] = wb; lsbx[sub] = sbx; lsby[sub] = sby; }
    __syncthreads();

    if (tid < 64) {
        float W  = lw[0][tid] + lw[1][tid] + lw[2][tid] + lw[3][tid];
        float SX = lsx[0][tid] + lsx[1][tid] + lsx[2][tid] + lsx[3][tid];
        float SY = lsy[0][tid] + lsy[1][tid] + lsy[2][tid] + lsy[3][tid];
        float wsx = W * SX, wsy = W * SY;

        float WB  = lwb[0] + lwb[1] + lwb[2] + lwb[3];
        float wbx = WB * (lsbx[0] + lsbx[1] + lsbx[2] + lsbx[3]);
        float wby = WB * (lsby[0] + lsby[1] + lsby[2] + lsby[3]);

        int tt = chunk * 64 + tid;
        *(float2*)(ws + tt * 32 + j * 2) = make_float2(wsx, wsy);

        float nx = __shfl_down(wsx, 1, 64);
        float ny = __shfl_down(wsy, 1, 64);
        if (tid == 63) { nx = wbx; ny = wby; }
        float cx = nx - 2.f * wsx;
        float cy = ny - 2.f * wsy;
        if (tt == TT - 1) { cx = 0.f; cy = 0.f; }  // coef[T-1] unused
        *(float2*)(coef + tt * 32 + j * 2) = make_float2(cx, cy);
    }
}

// out[2k+c] = sum_{u=k-1}^{T-2} sum_j pg[k,u,j,c]*coef[u,j,c]
//           + sum_j pg[k,k-2,j,c]*ws[k-1,j,c]   (k>=2 boundary slice)
// Block b handles k1=b+1 and k2=1023-b (equal total work).
__global__ __launch_bounds__(512) void grad_kernel(const float* __restrict__ pg,
                                                   const float* __restrict__ ws,
                                                   const float* __restrict__ coef,
                                                   float* __restrict__ out) {
    const int b = blockIdx.x;
    const int tid = threadIdx.x;
    __shared__ float sx[8], sy[8];

    if (b == 0 && tid < 2) out[tid] = 0.0f;  // k = 0 masked out

    const int k1 = b + 1;          // 1..512
    const int k2 = TT - 1 - b;     // 1023..512
    const float4* __restrict__ coef4 = reinterpret_cast<const float4*>(coef);

    for (int pass = 0; pass < 2; ++pass) {
        if (pass && k2 == k1) break;   // b==511 duplicate (uniform branch)
        const int k = pass ? k2 : k1;
        const float4* __restrict__ row4 =
            reinterpret_cast<const float4*>(pg + (size_t)k * (TT * AA * 2));

        float accx = 0.0f, accy = 0.0f;

        // boundary slice u = k-2: coefficient is ws[k-1] only
        if (k >= 2 && tid < 8) {
            int q = (k - 2) * 8 + tid;
            float4 p  = row4[q];
            float4 wv = *reinterpret_cast<const float4*>(ws + (k - 1) * 32 + tid * 4);
            accx += p.x * wv.x + p.z * wv.z;
            accy += p.y * wv.y + p.w * wv.w;
        }

        // main suffix u in [k-1, T-2]; 4-way unrolled for ILP
        const int end = (TT - 1) * 8;
        int i = (k - 1) * 8 + tid;
        for (; i + 1536 < end; i += 2048) {
            float4 p0 = row4[i];         float4 c0 = coef4[i];
            float4 p1 = row4[i + 512];   float4 c1 = coef4[i + 512];
            float4 p2 = row4[i + 1024];  float4 c2 = coef4[i + 1024];
            float4 p3 = row4[i + 1536];  float4 c3 = coef4[i + 1536];
            accx += p0.x * c0.x + p0.z * c0.z;
            accy += p0.y * c0.y + p0.w * c0.w;
            accx += p1.x * c1.x + p1.z * c1.z;
            accy += p1.y * c1.y + p1.w * c1.w;
            accx += p2.x * c2.x + p2.z * c2.z;
            accy += p2.y * c2.y + p2.w * c2.w;
            accx += p3.x * c3.x + p3.z * c3.z;
            accy += p3.y * c3.y + p3.w * c3.w;
        }
        for (; i < end; i += 512) {
            float4 p0 = row4[i];  float4 c0 = coef4[i];
            accx += p0.x * c0.x + p0.z * c0.z;
            accy += p0.y * c0.y + p0.w * c0.w;
        }

        // wave64 shuffle reduce
        for (int off = 32; off > 0; off >>= 1) {
            accx += __shfl_down(accx, off, 64);
            accy += __shfl_down(accy, off, 64);
        }
        if (pass) __syncthreads();  // LDS reuse barrier (uniform)
        int wave = tid >> 6, lane = tid & 63;
        if (lane == 0) { sx[wave] = accx; sy[wave] = accy; }
        __syncthreads();
        if (tid == 0) {
            float rx = 0.0f, ry = 0.0f;
            #pragma unroll
            for (int w2 = 0; w2 < 8; ++w2) { rx += sx[w2]; ry += sy[w2]; }
            out[2 * k + 0] = rx;
            out[2 * k + 1] = ry;
        }
    }
}

extern "C" void kernel_launch(void* const* d_in, const int* in_sizes, int n_in,
                              void* d_out, int out_size, void* d_ws, size_t ws_size,
                              hipStream_t stream) {
    const float* ado    = (const float*)d_in[0];
    const float* ado_wo = (const float*)d_in[1];
    const float* pg     = (const float*)d_in[2];
    float* out  = (float*)d_out;
    float* ws   = (float*)d_ws;                    // 32768 floats = 128 KB
    float* coef = (float*)d_ws + TT * AA * 2;      // 32768 floats = 128 KB

    wscoef_kernel<<<AA * (TT / 64), 256, 0, stream>>>(ado, ado_wo, ws, coef);
    grad_kernel<<<512, 512, 0, stream>>>(pg, ws, coef, out);
}